// Round 1
// baseline (519.489 us; speedup 1.0000x reference)
//
#include <hip/hip_runtime.h>

#define B_ 256
#define S_ 512
#define V_ 50000
#define D_ 256
#define L_ 128
#define TM 64

// ws layout (float units):
// ws[0] = sq_acc (float), ws[1] = kl_acc (float), ws[2] = valid_cnt (int)
// ws[4 .. 4+B*D)            = enc
// ws[4+B*D .. 4+B*D+B)      = lens (int)
// ws[4+B*D+B .. +B*D)       = Q

__global__ void init_kernel(float* ws) {
    ws[0] = 0.f;
    ws[1] = 0.f;
    ((int*)ws)[2] = 0;
}

__global__ __launch_bounds__(256) void enc_kernel(
    const int* __restrict__ vocab, const int* __restrict__ order,
    const int* __restrict__ mask, const float* __restrict__ emb,
    float* __restrict__ enc, int* __restrict__ lens) {
    __shared__ int s_id1[S_];
    __shared__ int s_id2[S_];
    __shared__ int s_cnt;
    const int b = blockIdx.x;
    const int tid = threadIdx.x;
    if (tid == 0) s_cnt = 0;
    __syncthreads();
    int local = 0;
    for (int j = tid; j < S_; j += 256) {
        int mk = mask[b * S_ + j];
        int id1 = -1, id2 = -1;
        if (mk) {
            local++;
            id1 = vocab[b * S_ + j];
            if (j == 0) {
                id2 = 1;  // BOS override at position 0
            } else {
                int oi = order[(size_t)(b * S_ + j) * 6];
                if (oi == -1) oi = 1;
                // parent gathers from the MASKED vocab (vt), so masked-out -> PAD(0)
                id2 = mask[b * S_ + oi] ? vocab[b * S_ + oi] : 0;
            }
        }
        s_id1[j] = id1;
        s_id2[j] = id2;
    }
    if (local) atomicAdd(&s_cnt, local);
    __syncthreads();
    const int cnt = s_cnt;  // prefix mask: valid j are exactly [0, cnt)
    float acc = 0.f;
#pragma unroll 4
    for (int j = 0; j < cnt; ++j) {
        acc += emb[(size_t)s_id1[j] * D_ + tid] + emb[(size_t)s_id2[j] * D_ + tid];
    }
    enc[b * D_ + tid] = acc / fmaxf((float)cnt, 1.f);
    if (tid == 0) lens[b] = cnt;
}

__global__ __launch_bounds__(256) void latent_kernel(
    const float* __restrict__ enc, const float* __restrict__ eps,
    const float* __restrict__ Wm, const float* __restrict__ bm,
    const float* __restrict__ Wv, const float* __restrict__ bv,
    const float* __restrict__ Wlin, const float* __restrict__ blin,
    const float* __restrict__ Wout, const float* __restrict__ bout,
    float* __restrict__ Q, float* __restrict__ kl_acc) {
    __shared__ float s_enc[D_];
    __shared__ float s_mean[L_], s_lv[L_], s_z[L_], s_mem[D_];
    __shared__ float s_red[256];
    const int b = blockIdx.x;
    const int tid = threadIdx.x;
    s_enc[tid] = enc[b * D_ + tid];
    __syncthreads();
    const int l = tid & (L_ - 1);
    const float* W = (tid < L_) ? Wm : Wv;
    const float* bb = (tid < L_) ? bm : bv;
    float dot = bb[l];
    for (int d = 0; d < D_; ++d) dot = fmaf(s_enc[d], W[d * L_ + l], dot);
    if (tid < L_) s_mean[l] = dot; else s_lv[l] = dot;
    __syncthreads();
    float klp = 0.f;
    if (tid < L_) {
        float mn = s_mean[l], lv = s_lv[l];
        s_z[l] = mn + eps[b * L_ + l] * expf(0.5f * lv);
        klp = 1.f + lv - mn * mn - expf(lv);
    }
    s_red[tid] = klp;
    __syncthreads();
    for (int s = 128; s > 0; s >>= 1) {
        if (tid < s) s_red[tid] += s_red[tid + s];
        __syncthreads();
    }
    if (tid == 0) atomicAdd(kl_acc, s_red[0]);
    // memory = z @ Wlin + blin  (kept in LDS only)
    float mem = blin[tid];
    for (int l2 = 0; l2 < L_; ++l2) mem = fmaf(s_z[l2], Wlin[l2 * D_ + tid], mem);
    s_mem[tid] = mem;
    __syncthreads();
    // Q = memory @ Wout + bout
    float q = bout[tid];
    for (int k = 0; k < D_; ++k) q = fmaf(s_mem[k], Wout[k * D_ + tid], q);
    Q[b * D_ + tid] = q;
}

__global__ __launch_bounds__(256) void loss_kernel(
    const int* __restrict__ vocab, const float* __restrict__ emb,
    const float* __restrict__ Wout, const float* __restrict__ Q,
    const int* __restrict__ lens, float* __restrict__ sq_acc,
    int* __restrict__ valid_acc) {
    __shared__ __align__(16) float sA[D_ * TM];  // transposed A tile, xor-swizzled
    __shared__ int s_inp[TM], s_tgt[TM];
    __shared__ float s_red[256];
    const int b = blockIdx.y;
    const int j0 = blockIdx.x * TM;
    const int tid = threadIdx.x;
    const int len = lens[b];
    if (j0 > len) return;  // uniform across block; whole tile invalid

    if (tid < TM) {
        int j = j0 + tid;
        int inp_id = -1, tgt_id = -1;
        if (j <= len) {  // valid positions are exactly j in [0, len]
            inp_id = (j == 0) ? 1 : vocab[b * S_ + j - 1];
            // tgt: vocab[j] for j<len; at j==len: EOS if len<S, else roll-wrap BOS
            tgt_id = (j < len) ? vocab[b * S_ + j] : ((len < S_) ? 2 : 1);
        }
        s_inp[tid] = inp_id;
        s_tgt[tid] = tgt_id;
    }
    __syncthreads();

    // stage A^T into LDS: sA[k*TM + (m ^ swz(k))] = emb[inp_id[m]][k]
    const float4* emb4 = (const float4*)emb;
#pragma unroll
    for (int i = 0; i < 16; ++i) {
        int f = i * 256 + tid;
        int m = f >> 6;      // position within tile
        int c4 = f & 63;     // float4 index along k
        int id = s_inp[m];
        if (id < 0) id = 0;
        float4 v = emb4[(size_t)id * (D_ / 4) + c4];
        int swz = (c4 & 15) << 2;  // == ((k>>2)&15)<<2 for k=4*c4..4*c4+3
        int base = (c4 * 4) * TM + (m ^ swz);
        sA[base] = v.x;
        sA[base + TM] = v.y;
        sA[base + 2 * TM] = v.z;
        sA[base + 3 * TM] = v.w;
    }
    float q = Q[b * D_ + tid];
    __syncthreads();

    float acc[TM];
#pragma unroll
    for (int m = 0; m < TM; ++m) acc[m] = 0.f;

    const float* wp = Wout + tid;
    for (int k = 0; k < D_; ++k) {
        float w = wp[k * D_];
        int swz = ((k >> 2) & 15) << 2;
        const float* row = &sA[k * TM];
#pragma unroll
        for (int mg = 0; mg < 16; ++mg) {
            float4 a = *(const float4*)(row + ((mg * 4) ^ swz));
            acc[mg * 4 + 0] = fmaf(a.x, w, acc[mg * 4 + 0]);
            acc[mg * 4 + 1] = fmaf(a.y, w, acc[mg * 4 + 1]);
            acc[mg * 4 + 2] = fmaf(a.z, w, acc[mg * 4 + 2]);
            acc[mg * 4 + 3] = fmaf(a.w, w, acc[mg * 4 + 3]);
        }
    }

    float tsum = 0.f;
#pragma unroll
    for (int m = 0; m < TM; ++m) {
        int tg = s_tgt[m];
        if (tg >= 0) {  // uniform across block
            float t = emb[(size_t)tg * D_ + tid];
            float diff = acc[m] + q - t;
            tsum = fmaf(diff, diff, tsum);
        }
    }
    s_red[tid] = tsum;
    __syncthreads();
    for (int s = 128; s > 0; s >>= 1) {
        if (tid < s) s_red[tid] += s_red[tid + s];
        __syncthreads();
    }
    if (tid == 0) {
        atomicAdd(sq_acc, s_red[0]);
        atomicAdd(valid_acc, min(len, j0 + TM - 1) - j0 + 1);
    }
}

__global__ void finalize_kernel(const float* __restrict__ ws, float* __restrict__ out) {
    float sq = ws[0];
    float kl = ws[1];
    int vc = ((const int*)ws)[2];
    long long denom = (long long)vc * D_;
    if (denom < 1) denom = 1;
    out[0] = sq / (float)denom;
    out[1] = -0.5f * kl / (float)B_;
}

extern "C" void kernel_launch(void* const* d_in, const int* in_sizes, int n_in,
                              void* d_out, int out_size, void* d_ws, size_t ws_size,
                              hipStream_t stream) {
    const int* vocab = (const int*)d_in[0];
    const int* order = (const int*)d_in[1];
    const int* mask  = (const int*)d_in[2];
    const float* eps  = (const float*)d_in[3];
    const float* emb  = (const float*)d_in[4];
    const float* Wm   = (const float*)d_in[5];
    const float* bm   = (const float*)d_in[6];
    const float* Wv   = (const float*)d_in[7];
    const float* bv   = (const float*)d_in[8];
    const float* Wlin = (const float*)d_in[9];
    const float* blin = (const float*)d_in[10];
    const float* Wout = (const float*)d_in[11];
    const float* bout = (const float*)d_in[12];

    float* ws = (float*)d_ws;
    float* enc = ws + 4;
    int* lens = (int*)(ws + 4 + B_ * D_);
    float* Q = ws + 4 + B_ * D_ + B_;

    init_kernel<<<1, 1, 0, stream>>>(ws);
    enc_kernel<<<B_, 256, 0, stream>>>(vocab, order, mask, emb, enc, lens);
    latent_kernel<<<B_, 256, 0, stream>>>(enc, eps, Wm, bm, Wv, bv, Wlin, blin,
                                          Wout, bout, Q, ws + 1);
    loss_kernel<<<dim3((S_ / TM) + 1, B_), 256, 0, stream>>>(vocab, emb, Wout, Q,
                                                             lens, ws, (int*)ws + 2);
    finalize_kernel<<<1, 1, 0, stream>>>(ws, (float*)d_out);
}

// Round 2
// 214.685 us; speedup vs baseline: 2.4198x; 2.4198x over previous
//
#include <hip/hip_runtime.h>

#define B_ 256
#define S_ 512
#define V_ 50000
#define D_ 256
#define L_ 128

typedef __attribute__((ext_vector_type(8))) short short8;
typedef __attribute__((ext_vector_type(4))) float floatx4;

// ws layout (float units):
// [0] sq_acc (f32), [1] kl_acc (f32), [2] valid_cnt (i32)
// [16 .. 16+65536)          enc   (256x256 f32)
// [65552 .. +256)           lens  (256 i32)
// [65808 .. +65536)         Q     (256x256 f32)
// [131344 .. +32768 floats) Wt    (256x256 bf16 = Wout^T)
#define OFF_ENC  16
#define OFF_LENS (OFF_ENC + B_ * D_)
#define OFF_Q    (OFF_LENS + B_)
#define OFF_WT   (OFF_Q + B_ * D_)

__device__ __forceinline__ unsigned short f2bf(float x) {
    unsigned u = __float_as_uint(x);
    u += 0x7FFFu + ((u >> 16) & 1u);
    return (unsigned short)(u >> 16);
}

// ---- Wout (256x256 f32, row-major [k][n]) -> Wt (bf16, [n][k]) ----
__global__ __launch_bounds__(256) void wt_kernel(const float* __restrict__ Wout,
                                                 unsigned short* __restrict__ Wt) {
    __shared__ float sT[64][65];
    const int k0 = blockIdx.x * 64, n0 = blockIdx.y * 64;
    const int c = threadIdx.x & 63, rg = threadIdx.x >> 6;
#pragma unroll
    for (int i = 0; i < 16; ++i) {
        int r = rg * 16 + i;
        sT[c][r] = Wout[(k0 + r) * D_ + n0 + c];  // coalesced read
    }
    __syncthreads();
#pragma unroll
    for (int i = 0; i < 16; ++i) {
        int r = rg * 16 + i;
        Wt[(size_t)(n0 + r) * D_ + k0 + c] = f2bf(sT[r][c]);
    }
}

// ---- enc: masked mean of emb[vt]+emb[parent]; also zeroes accumulators ----
__global__ __launch_bounds__(1024) void enc_kernel(
    const int* __restrict__ vocab, const int* __restrict__ order,
    const int* __restrict__ mask, const float* __restrict__ emb,
    float* __restrict__ enc, int* __restrict__ lens, float* __restrict__ ctrl) {
    __shared__ int s_id1[S_];
    __shared__ int s_id2[S_];
    __shared__ float s_part[3][D_];
    __shared__ int s_cnt;
    const int b = blockIdx.x;
    const int tid = threadIdx.x;
    if (tid == 0) s_cnt = 0;
    if (b == 0 && tid < 3) ((int*)ctrl)[tid] = 0;  // sq, kl, valid_cnt
    __syncthreads();
    if (tid < S_) {
        int j = tid;
        int mk = mask[b * S_ + j];
        int id1 = 0, id2 = 0;
        if (mk) {
            id1 = vocab[b * S_ + j];
            if (j == 0) {
                id2 = 1;  // BOS at position 0
            } else {
                int oi = order[(size_t)(b * S_ + j) * 6];
                if (oi == -1) oi = 1;
                id2 = mask[b * S_ + oi] ? vocab[b * S_ + oi] : 0;  // parent from vt
            }
        }
        s_id1[j] = id1;
        s_id2[j] = id2;
        unsigned long long bal = __ballot(mk != 0);
        if ((tid & 63) == 0) atomicAdd(&s_cnt, __popcll(bal));
    }
    __syncthreads();
    const int cnt = s_cnt;  // prefix mask: valid j = [0, cnt)
    const int d = tid & 255, q = tid >> 8;
    const int H = (cnt + 3) >> 2;
    const int jbeg = q * H, jend = min(cnt, jbeg + H);
    float acc = 0.f;
#pragma unroll 4
    for (int j = jbeg; j < jend; ++j) {
        acc += emb[(size_t)s_id1[j] * D_ + d] + emb[(size_t)s_id2[j] * D_ + d];
    }
    if (q) s_part[q - 1][d] = acc;
    __syncthreads();
    if (q == 0) {
        acc += s_part[0][d] + s_part[1][d] + s_part[2][d];
        enc[b * D_ + d] = acc / fmaxf((float)cnt, 1.f);
        if (d == 0) lens[b] = cnt;
    }
}

// ---- latent: mean/log_var/z/kl, memory, Q = memory@Wout + bout ----
__global__ __launch_bounds__(256) void latent_kernel(
    const float* __restrict__ enc, const float* __restrict__ eps,
    const float* __restrict__ Wm, const float* __restrict__ bm,
    const float* __restrict__ Wv, const float* __restrict__ bv,
    const float* __restrict__ Wlin, const float* __restrict__ blin,
    const float* __restrict__ Wout, const float* __restrict__ bout,
    float* __restrict__ Q, float* __restrict__ kl_acc) {
    __shared__ float s_enc[D_];
    __shared__ float s_mean[L_], s_lv[L_], s_z[L_], s_mem[D_];
    __shared__ float s_red[256];
    const int b = blockIdx.x;
    const int tid = threadIdx.x;
    s_enc[tid] = enc[b * D_ + tid];
    __syncthreads();
    const int l = tid & (L_ - 1);
    const float* W = (tid < L_) ? Wm : Wv;
    const float* bb = (tid < L_) ? bm : bv;
    float dot = bb[l];
    for (int d = 0; d < D_; ++d) dot = fmaf(s_enc[d], W[d * L_ + l], dot);
    if (tid < L_) s_mean[l] = dot; else s_lv[l] = dot;
    __syncthreads();
    float klp = 0.f;
    if (tid < L_) {
        float mn = s_mean[l], lv = s_lv[l];
        s_z[l] = mn + eps[b * L_ + l] * expf(0.5f * lv);
        klp = 1.f + lv - mn * mn - expf(lv);
    }
    s_red[tid] = klp;
    __syncthreads();
    for (int s = 128; s > 0; s >>= 1) {
        if (tid < s) s_red[tid] += s_red[tid + s];
        __syncthreads();
    }
    if (tid == 0) atomicAdd(kl_acc, s_red[0]);
    float mem = blin[tid];
    for (int l2 = 0; l2 < L_; ++l2) mem = fmaf(s_z[l2], Wlin[l2 * D_ + tid], mem);
    s_mem[tid] = mem;
    __syncthreads();
    float qv = bout[tid];
    for (int k = 0; k < D_; ++k) qv = fmaf(s_mem[k], Wout[k * D_ + tid], qv);
    Q[b * D_ + tid] = qv;
}

// ---- loss: bf16 MFMA GEMM (64x256 tile) + fused epilogue ----
#define SAP 264  // sA row stride in bf16 (256 + 8 pad: 2-way bank pattern = free)

__global__ __launch_bounds__(256) void loss_kernel(
    const int* __restrict__ vocab, const float* __restrict__ emb,
    const unsigned short* __restrict__ Wt, const float* __restrict__ Q,
    const int* __restrict__ lens, float* __restrict__ sq_acc,
    int* __restrict__ valid_acc) {
    __shared__ __align__(16) unsigned short sA[64 * SAP];
    __shared__ int s_inp[64], s_tgt[64];
    __shared__ float s_wred[4];
    const int b = blockIdx.y;
    const int j0 = blockIdx.x * 64;
    const int tid = threadIdx.x;
    const int len = lens[b];
    if (j0 > len) return;  // block-uniform

    if (tid < 64) {
        int j = j0 + tid;
        int inp_id = 0, tgt_id = -1;
        if (j <= len) {  // valid positions: j in [0, len]
            inp_id = (j == 0) ? 1 : vocab[b * S_ + j - 1];
            // tgt: vocab[j] for j<len; j==len: EOS, except len==S -> roll-wrap BOS
            tgt_id = (j < len) ? vocab[b * S_ + j] : ((len < S_) ? 2 : 1);
        }
        s_inp[tid] = inp_id;
        s_tgt[tid] = tgt_id;
    }
    __syncthreads();

    // stage A tile (inp-row embeddings) as bf16 into LDS
    const float4* emb4 = (const float4*)emb;
#pragma unroll
    for (int i = 0; i < 16; ++i) {
        int f = i * 256 + tid;
        int m = f >> 6, c4 = f & 63;
        float4 v = emb4[(size_t)s_inp[m] * (D_ / 4) + c4];
        uint2 h;
        h.x = (unsigned)f2bf(v.x) | ((unsigned)f2bf(v.y) << 16);
        h.y = (unsigned)f2bf(v.z) | ((unsigned)f2bf(v.w) << 16);
        *(uint2*)(&sA[m * SAP + c4 * 4]) = h;
    }
    __syncthreads();

    const int wv = tid >> 6, lane = tid & 63;
    const int lo = lane & 15, hi = lane >> 4;

    floatx4 acc[4][4];
#pragma unroll
    for (int mt = 0; mt < 4; ++mt)
#pragma unroll
        for (int nt = 0; nt < 4; ++nt) acc[mt][nt] = (floatx4){0.f, 0.f, 0.f, 0.f};

    // A frag: A[m=lo][k=hi*8+j]; B frag: Wt[n=lo][k=hi*8+j] (Wt = Wout^T)
    const unsigned short* arow = sA + lo * SAP + hi * 8;
    const unsigned short* wrow = Wt + (size_t)(wv * 64 + lo) * D_ + hi * 8;

    for (int kk = 0; kk < 8; ++kk) {
        const int k0 = kk * 32;
        short8 bfr[4], afr[4];
#pragma unroll
        for (int nt = 0; nt < 4; ++nt)
            bfr[nt] = *(const short8*)(wrow + nt * 16 * D_ + k0);
#pragma unroll
        for (int mt = 0; mt < 4; ++mt)
            afr[mt] = *(const short8*)(arow + mt * 16 * SAP + k0);
#pragma unroll
        for (int mt = 0; mt < 4; ++mt)
#pragma unroll
            for (int nt = 0; nt < 4; ++nt)
                acc[mt][nt] = __builtin_amdgcn_mfma_f32_16x16x32_bf16(
                    afr[mt], bfr[nt], acc[mt][nt], 0, 0, 0);
    }

    // epilogue: D[row][col] at col=lo, row=hi*4+r
    float lsum = 0.f;
#pragma unroll
    for (int nt = 0; nt < 4; ++nt) {
        const int n = wv * 64 + nt * 16 + lo;
        const float qv = Q[b * D_ + n];
#pragma unroll
        for (int mt = 0; mt < 4; ++mt) {
#pragma unroll
            for (int r = 0; r < 4; ++r) {
                const int row = mt * 16 + hi * 4 + r;
                const int tg = s_tgt[row];
                if (tg >= 0) {
                    float t = emb[(size_t)tg * D_ + n];
                    float d = acc[mt][nt][r] + qv - t;
                    lsum = fmaf(d, d, lsum);
                }
            }
        }
    }
#pragma unroll
    for (int off = 32; off; off >>= 1) lsum += __shfl_down(lsum, off, 64);
    if (lane == 0) s_wred[wv] = lsum;
    __syncthreads();
    if (tid == 0) {
        atomicAdd(sq_acc, s_wred[0] + s_wred[1] + s_wred[2] + s_wred[3]);
        atomicAdd(valid_acc, min(len, j0 + 63) - j0 + 1);
    }
}

__global__ void finalize_kernel(const float* __restrict__ ws, float* __restrict__ out) {
    float sq = ws[0];
    float kl = ws[1];
    int vc = ((const int*)ws)[2];
    long long denom = (long long)vc * D_;
    if (denom < 1) denom = 1;
    out[0] = sq / (float)denom;
    out[1] = -0.5f * kl / (float)B_;
}

extern "C" void kernel_launch(void* const* d_in, const int* in_sizes, int n_in,
                              void* d_out, int out_size, void* d_ws, size_t ws_size,
                              hipStream_t stream) {
    const int* vocab = (const int*)d_in[0];
    const int* order = (const int*)d_in[1];
    const int* mask  = (const int*)d_in[2];
    const float* eps  = (const float*)d_in[3];
    const float* emb  = (const float*)d_in[4];
    const float* Wm   = (const float*)d_in[5];
    const float* bm   = (const float*)d_in[6];
    const float* Wv   = (const float*)d_in[7];
    const float* bv   = (const float*)d_in[8];
    const float* Wlin = (const float*)d_in[9];
    const float* blin = (const float*)d_in[10];
    const float* Wout = (const float*)d_in[11];
    const float* bout = (const float*)d_in[12];

    float* ws = (float*)d_ws;
    float* enc = ws + OFF_ENC;
    int* lens = (int*)(ws + OFF_LENS);
    float* Q = ws + OFF_Q;
    unsigned short* Wt = (unsigned short*)(ws + OFF_WT);

    wt_kernel<<<dim3(4, 4), 256, 0, stream>>>(Wout, Wt);
    enc_kernel<<<B_, 1024, 0, stream>>>(vocab, order, mask, emb, enc, lens, ws);
    latent_kernel<<<B_, 256, 0, stream>>>(enc, eps, Wm, bm, Wv, bv, Wlin, blin,
                                          Wout, bout, Q, ws + 1);
    loss_kernel<<<dim3((S_ / 64) + 1, B_), 256, 0, stream>>>(vocab, emb, Wt, Q,
                                                             lens, ws, (int*)ws + 2);
    finalize_kernel<<<1, 1, 0, stream>>>(ws, (float*)d_out);
}

// Round 3
// 204.209 us; speedup vs baseline: 2.5439x; 1.0513x over previous
//
#include <hip/hip_runtime.h>

#define B_ 256
#define S_ 512
#define V_ 50000
#define D_ 256
#define L_ 128

typedef __attribute__((ext_vector_type(8))) short short8;
typedef __attribute__((ext_vector_type(4))) float floatx4;

// ws layout (float/int units):
// [0] sq_acc (f32), [1] kl_acc (f32), [2] valid_cnt (i32), [3] wl_cnt (i32)
// [16 .. +256)      lens (i32)
// [272 .. +65536)   Q (256x256 f32)
// [65808 .. +2304)  worklist ints: (b<<8)|tile
// [68112 .. +32768) Wt (256x256 bf16 = Wout^T)
#define OFF_LENS 16
#define OFF_Q    (OFF_LENS + B_)
#define OFF_WL   (OFF_Q + B_ * D_)
#define OFF_WT   (OFF_WL + 2304)

__device__ __forceinline__ unsigned short f2bf(float x) {
    unsigned u = __float_as_uint(x);
    u += 0x7FFFu + ((u >> 16) & 1u);
    return (unsigned short)(u >> 16);
}
__device__ __forceinline__ unsigned pk2(float a, float b) {
    return (unsigned)f2bf(a) | ((unsigned)f2bf(b) << 16);
}

__device__ __forceinline__ void row_to_lds(const float* gbase, float* lds_row, int lane) {
    const float* gp = gbase + lane * 4;  // 16B per lane, 64 lanes = 1KB row
    __builtin_amdgcn_global_load_lds((const __attribute__((address_space(1))) void*)gp,
                                     (__attribute__((address_space(3))) void*)lds_row,
                                     16, 0, 0);
}

// ---- Wout (f32 [k][n]) -> Wt (bf16 [n][k]); also zero accumulators ----
__global__ __launch_bounds__(256) void wt_kernel(const float* __restrict__ Wout,
                                                 unsigned short* __restrict__ Wt,
                                                 int* __restrict__ ctrl) {
    __shared__ float sT[64][65];
    if (blockIdx.x == 0 && blockIdx.y == 0 && threadIdx.x < 4) ctrl[threadIdx.x] = 0;
    const int k0 = blockIdx.x * 64, n0 = blockIdx.y * 64;
    const int c = threadIdx.x & 63, rg = threadIdx.x >> 6;
#pragma unroll
    for (int i = 0; i < 16; ++i) {
        int r = rg * 16 + i;
        sT[c][r] = Wout[(k0 + r) * D_ + n0 + c];
    }
    __syncthreads();
#pragma unroll
    for (int i = 0; i < 16; ++i) {
        int r = rg * 16 + i;
        Wt[(size_t)(n0 + r) * D_ + k0 + c] = f2bf(sT[r][c]);
    }
}

// ---- fused enc + latent + worklist plan (one block per b) ----
__global__ __launch_bounds__(1024) void enclat_kernel(
    const int* __restrict__ vocab, const int* __restrict__ order,
    const int* __restrict__ mask, const float* __restrict__ emb,
    const float* __restrict__ eps,
    const float* __restrict__ Wm, const float* __restrict__ bm,
    const float* __restrict__ Wv, const float* __restrict__ bv,
    const float* __restrict__ Wlin, const float* __restrict__ blin,
    const float* __restrict__ Wout, const float* __restrict__ bout,
    int* __restrict__ lens, float* __restrict__ Q,
    int* __restrict__ wl, int* __restrict__ ctrl) {
    __shared__ int s_id1[S_], s_id2[S_];
    __shared__ float4 s_part[15 * 64];
    __shared__ float s_enc[D_];
    __shared__ float s_mean[L_], s_lv[L_], s_z[L_], s_mem[D_];
    __shared__ float s_red[256];
    __shared__ int s_cnt;
    const int b = blockIdx.x;
    const int tid = threadIdx.x;
    if (tid == 0) s_cnt = 0;
    __syncthreads();
    if (tid < S_) {
        int j = tid;
        int mk = mask[b * S_ + j];
        int id1 = 0, id2 = 0;
        if (mk) {
            id1 = vocab[b * S_ + j];
            if (j == 0) {
                id2 = 1;  // BOS at position 0
            } else {
                int oi = order[(size_t)(b * S_ + j) * 6];
                if (oi == -1) oi = 1;
                id2 = mask[b * S_ + oi] ? vocab[b * S_ + oi] : 0;  // parent from vt
            }
        }
        s_id1[j] = id1;
        s_id2[j] = id2;
        unsigned long long bal = __ballot(mk != 0);
        if ((tid & 63) == 0) atomicAdd(&s_cnt, __popcll(bal));
    }
    __syncthreads();
    const int cnt = s_cnt;  // prefix mask: valid j = [0, cnt)
    if (tid == 0) {
        lens[b] = cnt;
        int nt = (cnt >> 6) + 1;  // tiles cover j in [0, cnt]
        int base = atomicAdd(&ctrl[3], nt);
        for (int t = 0; t < nt; ++t) wl[base + t] = (b << 8) | t;
    }
    // 16-way split-j gather, float4 per thread
    const int jg = tid >> 6, d4 = tid & 63;
    const float4* emb4 = (const float4*)emb;
    float4 a = {0.f, 0.f, 0.f, 0.f};
#pragma unroll 4
    for (int j = jg; j < cnt; j += 16) {
        float4 x = emb4[(size_t)s_id1[j] * 64 + d4];
        float4 y = emb4[(size_t)s_id2[j] * 64 + d4];
        a.x += x.x + y.x; a.y += x.y + y.y; a.z += x.z + y.z; a.w += x.w + y.w;
    }
    if (jg) s_part[(jg - 1) * 64 + d4] = a;
    __syncthreads();
    if (jg == 0) {
#pragma unroll
        for (int g = 0; g < 15; ++g) {
            float4 p = s_part[g * 64 + d4];
            a.x += p.x; a.y += p.y; a.z += p.z; a.w += p.w;
        }
        float inv = 1.f / fmaxf((float)cnt, 1.f);
        a.x *= inv; a.y *= inv; a.z *= inv; a.w *= inv;
        ((float4*)s_enc)[d4] = a;
    }
    __syncthreads();
    // ---- latent (threads < 256) ----
    float dot = 0.f;
    if (tid < 256) {
        const int l = tid & (L_ - 1);
        const float* W = (tid < L_) ? Wm : Wv;
        const float* bb = (tid < L_) ? bm : bv;
        dot = bb[l];
        for (int d = 0; d < D_; ++d) dot = fmaf(s_enc[d], W[d * L_ + l], dot);
        if (tid < L_) s_mean[l] = dot; else s_lv[l] = dot;
    }
    __syncthreads();
    float klp = 0.f;
    if (tid < L_) {
        float mn = s_mean[tid], lv = s_lv[tid];
        s_z[tid] = mn + eps[b * L_ + tid] * expf(0.5f * lv);
        klp = 1.f + lv - mn * mn - expf(lv);
    }
    if (tid < 256) s_red[tid] = klp;
    __syncthreads();
    for (int s = 128; s > 0; s >>= 1) {
        if (tid < s) s_red[tid] += s_red[tid + s];
        __syncthreads();
    }
    if (tid == 0) atomicAdd((float*)&ctrl[1], s_red[0]);
    if (tid < 256) {
        float mem = blin[tid];
        for (int l2 = 0; l2 < L_; ++l2) mem = fmaf(s_z[l2], Wlin[l2 * D_ + tid], mem);
        s_mem[tid] = mem;
    }
    __syncthreads();
    if (tid < 256) {
        float qv = bout[tid];
        for (int k = 0; k < D_; ++k) qv = fmaf(s_mem[k], Wout[k * D_ + tid], qv);
        Q[b * D_ + tid] = qv;
    }
}

// ---- loss: persistent worklist + global_load_lds fp32 staging + bf16 MFMA ----
#define SAP 260  // fp32 LDS row stride (256 + 4; rows stay 16B aligned)

__global__ __launch_bounds__(256, 2) void loss_kernel(
    const int* __restrict__ vocab, const float* __restrict__ emb,
    const unsigned short* __restrict__ Wt, const float* __restrict__ Q,
    const int* __restrict__ lens, const int* __restrict__ wl,
    int* __restrict__ ctrl) {
    __shared__ __align__(16) float sA[64 * SAP];
    __shared__ int s_inp[64], s_tgt[64];
    __shared__ float s_wred[4];
    const int tid = threadIdx.x;
    const int wv = tid >> 6, lane = tid & 63;
    const int lo = lane & 15, hi = lane >> 4;
    const int nwork = ctrl[3];
    float* sq_acc = (float*)&ctrl[0];
    int* valid_acc = &ctrl[2];

    for (int it = blockIdx.x; it < nwork; it += gridDim.x) {
        const int e = wl[it];
        const int b = e >> 8;
        const int j0 = (e & 255) << 6;
        const int len = lens[b];
        __syncthreads();  // protect s_inp/s_tgt/sA reuse across items
        if (tid < 64) {
            int j = j0 + tid;
            int inp_id = 0, tgt_id = -1;
            if (j <= len) {  // valid positions: j in [0, len]
                inp_id = (j == 0) ? 1 : vocab[b * S_ + j - 1];
                // tgt: vocab[j] for j<len; j==len: EOS, except len==S -> roll-wrap BOS
                tgt_id = (j < len) ? vocab[b * S_ + j] : ((len < S_) ? 2 : 1);
            }
            s_inp[tid] = inp_id;
            s_tgt[tid] = tgt_id;
        }
        __syncthreads();
        // stage 16 rows per wave straight to LDS (no dest VGPRs, 16 in flight)
#pragma unroll
        for (int r = 0; r < 16; ++r) {
            const int m = wv * 16 + r;
            row_to_lds(emb + (size_t)s_inp[m] * D_, &sA[m * SAP], lane);
        }
        __syncthreads();  // vmcnt(0) drain: rows landed

        floatx4 acc[4][4];
#pragma unroll
        for (int mt = 0; mt < 4; ++mt)
#pragma unroll
            for (int nt = 0; nt < 4; ++nt) acc[mt][nt] = (floatx4){0.f, 0.f, 0.f, 0.f};

        const float* arow = &sA[lo * SAP + hi * 8];
        const unsigned short* wrow = Wt + (size_t)(wv * 64 + lo) * D_ + hi * 8;

        for (int kk = 0; kk < 8; ++kk) {
            const int k0 = kk * 32;
            short8 bfr[4], afr[4];
#pragma unroll
            for (int nt = 0; nt < 4; ++nt)
                bfr[nt] = *(const short8*)(wrow + nt * 16 * D_ + k0);
#pragma unroll
            for (int mt = 0; mt < 4; ++mt) {
                const float* ap = arow + mt * 16 * SAP + k0;
                float4 f0 = *(const float4*)(ap);
                float4 f1 = *(const float4*)(ap + 4);
                union { unsigned u[4]; short8 s; } cv;
                cv.u[0] = pk2(f0.x, f0.y);
                cv.u[1] = pk2(f0.z, f0.w);
                cv.u[2] = pk2(f1.x, f1.y);
                cv.u[3] = pk2(f1.z, f1.w);
                afr[mt] = cv.s;
            }
#pragma unroll
            for (int mt = 0; mt < 4; ++mt)
#pragma unroll
                for (int nt = 0; nt < 4; ++nt)
                    acc[mt][nt] = __builtin_amdgcn_mfma_f32_16x16x32_bf16(
                        afr[mt], bfr[nt], acc[mt][nt], 0, 0, 0);
        }

        // epilogue: D[row][col] at col=lo, row=hi*4+r
        float lsum = 0.f;
#pragma unroll
        for (int nt = 0; nt < 4; ++nt) {
            const int n = wv * 64 + nt * 16 + lo;
            const float qv = Q[b * D_ + n];
#pragma unroll
            for (int mt = 0; mt < 4; ++mt) {
#pragma unroll
                for (int r = 0; r < 4; ++r) {
                    const int row = mt * 16 + hi * 4 + r;
                    const int tg = s_tgt[row];
                    if (tg >= 0) {
                        float t = emb[(size_t)tg * D_ + n];
                        float d = acc[mt][nt][r] + qv - t;
                        lsum = fmaf(d, d, lsum);
                    }
                }
            }
        }
#pragma unroll
        for (int off = 32; off; off >>= 1) lsum += __shfl_down(lsum, off, 64);
        if (lane == 0) s_wred[wv] = lsum;
        __syncthreads();
        if (tid == 0) {
            atomicAdd(sq_acc, s_wred[0] + s_wred[1] + s_wred[2] + s_wred[3]);
            atomicAdd(valid_acc, min(len, j0 + 63) - j0 + 1);
        }
    }
}

__global__ void finalize_kernel(const float* __restrict__ ws, float* __restrict__ out) {
    float sq = ws[0];
    float kl = ws[1];
    int vc = ((const int*)ws)[2];
    long long denom = (long long)vc * D_;
    if (denom < 1) denom = 1;
    out[0] = sq / (float)denom;
    out[1] = -0.5f * kl / (float)B_;
}

extern "C" void kernel_launch(void* const* d_in, const int* in_sizes, int n_in,
                              void* d_out, int out_size, void* d_ws, size_t ws_size,
                              hipStream_t stream) {
    const int* vocab = (const int*)d_in[0];
    const int* order = (const int*)d_in[1];
    const int* mask  = (const int*)d_in[2];
    const float* eps  = (const float*)d_in[3];
    const float* emb  = (const float*)d_in[4];
    const float* Wm   = (const float*)d_in[5];
    const float* bm   = (const float*)d_in[6];
    const float* Wv   = (const float*)d_in[7];
    const float* bv   = (const float*)d_in[8];
    const float* Wlin = (const float*)d_in[9];
    const float* blin = (const float*)d_in[10];
    const float* Wout = (const float*)d_in[11];
    const float* bout = (const float*)d_in[12];

    float* ws = (float*)d_ws;
    int* ctrl = (int*)ws;
    int* lens = (int*)(ws + OFF_LENS);
    float* Q = ws + OFF_Q;
    int* wl = (int*)(ws + OFF_WL);
    unsigned short* Wt = (unsigned short*)(ws + OFF_WT);

    wt_kernel<<<dim3(4, 4), 256, 0, stream>>>(Wout, Wt, ctrl);
    enclat_kernel<<<B_, 1024, 0, stream>>>(vocab, order, mask, emb, eps, Wm, bm,
                                           Wv, bv, Wlin, blin, Wout, bout,
                                           lens, Q, wl, ctrl);
    loss_kernel<<<1024, 256, 0, stream>>>(vocab, emb, Wt, Q, lens, wl, ctrl);
    finalize_kernel<<<1, 1, 0, stream>>>(ws, (float*)d_out);
}